// Round 1
// baseline (335.393 us; speedup 1.0000x reference)
//
#include <hip/hip_runtime.h>

#define TT 512
#define BB 1024
#define VV 96
#define LL 48
#define TG (TT / 4)   // 128 groups of 4 timesteps
#define SLOT 52       // float4 slots per (b,tg) record: 49 used (blank + 48 labels), pad to 52 -> 832 B, 64B-aligned

__device__ __forceinline__ int f2i(float x) { return __float_as_int(x); }
__device__ __forceinline__ float i2f(int x) { return __int_as_float(x); }

template <int CTRL, int RM, int BM, bool BC>
__device__ __forceinline__ float dppf(float old, float src) {
    return i2f(__builtin_amdgcn_update_dpp(f2i(old), f2i(src), CTRL, RM, BM, BC));
}

// Full-wave sum via DPP butterfly (verified in prior rounds); broadcast via lane 63.
__device__ __forceinline__ float wave_sum(float v) {
    v += dppf<0xB1, 0xF, 0xF, true>(0.f, v);   // quad_perm [1,0,3,2]
    v += dppf<0x4E, 0xF, 0xF, true>(0.f, v);   // quad_perm [2,3,0,1]
    v += dppf<0x141, 0xF, 0xF, true>(0.f, v);  // row_half_mirror
    v += dppf<0x140, 0xF, 0xF, true>(0.f, v);  // row_mirror
    v += dppf<0x142, 0xA, 0xF, false>(0.f, v); // row_bcast15
    v += dppf<0x143, 0xC, 0xF, false>(0.f, v); // row_bcast31
    return i2f(__builtin_amdgcn_readlane(f2i(v), 63));
}

// Full-wave max (nonnegative inputs; old=0 is neutral).
__device__ __forceinline__ float wave_max(float v) {
    v = fmaxf(v, dppf<0xB1, 0xF, 0xF, true>(0.f, v));
    v = fmaxf(v, dppf<0x4E, 0xF, 0xF, true>(0.f, v));
    v = fmaxf(v, dppf<0x141, 0xF, 0xF, true>(0.f, v));
    v = fmaxf(v, dppf<0x140, 0xF, 0xF, true>(0.f, v));
    v = fmaxf(v, dppf<0x142, 0xA, 0xF, false>(0.f, v));
    v = fmaxf(v, dppf<0x143, 0xC, 0xF, false>(0.f, v));
    return i2f(__builtin_amdgcn_readlane(f2i(v), 63));
}

// ---------------------------------------------------------------------------
// Pass 1: emission table. One wave per (b, 4-timestep group).
// For each (t,b): softmax denominator + gather of the 49 needed vocab probs
// (blank + labels[0..47]), scaled by 96/denom. Written as [B, TG, SLOT] float4
// (float4 packs t = 4*tg .. 4*tg+3) so the scan pass streams contiguously.
// 131072 waves -> 8 waves/SIMD: VMEM latency hidden by TLP, memory-bound.
// ---------------------------------------------------------------------------
__global__ __launch_bounds__(256) void ctc_emit(
        const int* __restrict__ labels,
        const float* __restrict__ yp,
        float4* __restrict__ P) {
    const int l = threadIdx.x & 63;
    const int flat = blockIdx.x * 4 + (threadIdx.x >> 6);  // 0 .. B*TG-1
    const int tg = flat & (TG - 1);
    const int b = flat >> 7;                               // flat / TG
    const int* lb = labels + b * LL;

    const int cl = (l < 48) ? l : 47;  // float2 slot of the 96-wide row
    const size_t step2 = (size_t)BB * (VV / 2);
    const float2* rp = (const float2*)yp + (size_t)(4 * tg) * step2
                     + (size_t)b * (VV / 2) + cl;

    // issue all 4 row loads up front (4 outstanding per wave)
    float2 rr0 = rp[0];
    float2 rr1 = rp[step2];
    float2 rr2 = rp[2 * step2];
    float2 rr3 = rp[3 * step2];

    // output-lane j holds vocab id: j==0 -> blank(0), 1<=j<=48 -> labels[j-1]
    const int vj = (l >= 1 && l <= 48) ? lb[l - 1] : 0;
    const int pa = (vj >> 1) << 2;
    const int ps = vj & 1;

    auto emit1 = [&](float2 r) -> float {
        float ex0 = __expf(r.x), ex1 = __expf(r.y);
        float se = (l < 48) ? (ex0 + ex1) : 0.f;
        float tot = wave_sum(se);
        float r96 = 96.0f * __builtin_amdgcn_rcpf(tot);
        float gx = i2f(__builtin_amdgcn_ds_bpermute(pa, f2i(ex0)));
        float gy = i2f(__builtin_amdgcn_ds_bpermute(pa, f2i(ex1)));
        return (ps ? gy : gx) * r96;
    };
    float o0 = emit1(rr0);
    float o1 = emit1(rr1);
    float o2 = emit1(rr2);
    float o3 = emit1(rr3);

    if (l < SLOT) {
        P[(size_t)flat * SLOT + l] = make_float4(o0, o1, o2, o3);
    }
}

// ---------------------------------------------------------------------------
// Pass 2: the serial scan. One wave per batch element. Per 4-step group it
// reads ONE contiguous float4 per lane (832 B/record, sequential in t, 8-deep
// ring = 32 steps of prefetch cover), does 8 bpermutes (pipelined one group
// ahead) and 4 stageB updates. No exp / wave_sum / rcp on the critical path.
// State mapping, stageB, renorm, and final readout identical to the verified
// fused kernel.
// ---------------------------------------------------------------------------
__global__ __launch_bounds__(64) void ctc_scan(
        const int* __restrict__ labels,
        const float4* __restrict__ P,
        float* __restrict__ loss) {
    const int b = blockIdx.x;
    const int l = threadIdx.x;
    const int* lb = labels + b * LL;

    const bool odd = (l & 1);
    const int i0 = l >> 1;
    int i1 = (63 + l) >> 1; if (i1 > LL - 1) i1 = LL - 1;
    const int la0 = lb[i0];
    const int lp0 = lb[(i0 > 0) ? i0 - 1 : 0];
    const int la1 = lb[i1];
    const int lp1 = lb[(i1 > 0) ? i1 - 1 : 0];
    const bool v1 = (l <= 32);
    const bool skip0 = odd && (l >= 3) && (la0 != lp0);
    const bool skip1 = odd && v1 && (la1 != lp1);
    // record-slot index for each owned state (slot j: 0=blank, j=labels[j-1])
    const int a0 = (odd ? (i0 + 1) : 0) << 2;            // bpermute byte addr
    const int a1 = ((odd && v1) ? (i1 + 1) : 0) << 2;

    const int cl = (l < SLOT) ? l : SLOT - 1;
    const float4* gp = P + (size_t)b * ((size_t)TG * SLOT) + cl;

    float4 ring[8];
    #pragma unroll
    for (int j = 0; j < 8; ++j) ring[j] = gp[(size_t)j * SLOT];

    float A0, A1;   // alpha (linear, rescaled); A0: s=l, A1: s=64+l
    int S2 = 0;     // accumulated log2 scale removed by renorms

    // E double-buffer as named scalars (no runtime-indexed arrays -> no scratch)
    float C00, C01, C02, C03, C10, C11, C12, C13;
    float N00, N01, N02, N03, N10, N11, N12, N13;

    auto stageB = [&](float e0, float e1) {
        float a1_0 = dppf<0x138, 0xF, 0xF, false>(0.f, A0);      // wave_shr1
        float a2_0 = dppf<0x138, 0xF, 0xF, false>(0.f, a1_0);
        float b63 = i2f(__builtin_amdgcn_readlane(f2i(A0), 63));
        float b62 = i2f(__builtin_amdgcn_readlane(f2i(A0), 62));
        float a1_1 = dppf<0x138, 0xF, 0xF, false>(b63, A1);
        float a2_1 = dppf<0x138, 0xF, 0xF, false>(b62, a1_1);
        A0 = (A0 + a1_0 + (skip0 ? a2_0 : 0.f)) * e0;
        A1 = (A1 + a1_1 + (skip1 ? a2_1 : 0.f)) * e1;
    };

#define COMPUTE_E(r, O00, O01, O02, O03, O10, O11, O12, O13) \
    O00 = i2f(__builtin_amdgcn_ds_bpermute(a0, f2i((r).x))); \
    O10 = i2f(__builtin_amdgcn_ds_bpermute(a1, f2i((r).x))); \
    O01 = i2f(__builtin_amdgcn_ds_bpermute(a0, f2i((r).y))); \
    O11 = i2f(__builtin_amdgcn_ds_bpermute(a1, f2i((r).y))); \
    O02 = i2f(__builtin_amdgcn_ds_bpermute(a0, f2i((r).z))); \
    O12 = i2f(__builtin_amdgcn_ds_bpermute(a1, f2i((r).z))); \
    O03 = i2f(__builtin_amdgcn_ds_bpermute(a0, f2i((r).w))); \
    O13 = i2f(__builtin_amdgcn_ds_bpermute(a1, f2i((r).w)));

    // ---- group 0: t = 0..3 ----
    COMPUTE_E(ring[0], C00, C01, C02, C03, C10, C11, C12, C13);
    A0 = (l < 2) ? C00 : 0.f;  // t=0: only first blank & first label reachable
    A1 = 0.f;
    ring[0] = gp[(size_t)8 * SLOT];
    COMPUTE_E(ring[1], N00, N01, N02, N03, N10, N11, N12, N13);  // E(group 1)
    ring[1] = gp[(size_t)9 * SLOT];
    stageB(C01, C11);  // t=1
    stageB(C02, C12);  // t=2
    stageB(C03, C13);  // t=3

    // group g: 4 stageB with current E; compute E(g+1) from ring[(g+1)&7]
    // (slot passed as literal -> static register indexing); refill with g+9.
#define GROUP(g, slot, A00, A01, A02, A03, A10, A11, A12, A13, \
                       B00, B01, B02, B03, B10, B11, B12, B13) \
    stageB(A00, A10); \
    COMPUTE_E(ring[slot], B00, B01, B02, B03, B10, B11, B12, B13); \
    if ((g) + 9 < TG) ring[slot] = gp[(size_t)((g) + 9) * SLOT]; \
    stageB(A01, A11); \
    stageB(A02, A12); \
    stageB(A03, A13);

    // ---- prologue groups 1..6 (slots 2..7); odd g uses N, even g uses C ----
    GROUP(1, 2, N00, N01, N02, N03, N10, N11, N12, N13, C00, C01, C02, C03, C10, C11, C12, C13)
    GROUP(2, 3, C00, C01, C02, C03, C10, C11, C12, C13, N00, N01, N02, N03, N10, N11, N12, N13)
    GROUP(3, 4, N00, N01, N02, N03, N10, N11, N12, N13, C00, C01, C02, C03, C10, C11, C12, C13)
    GROUP(4, 5, C00, C01, C02, C03, C10, C11, C12, C13, N00, N01, N02, N03, N10, N11, N12, N13)
    GROUP(5, 6, N00, N01, N02, N03, N10, N11, N12, N13, C00, C01, C02, C03, C10, C11, C12, C13)
    GROUP(6, 7, C00, C01, C02, C03, C10, C11, C12, C13, N00, N01, N02, N03, N10, N11, N12, N13)

    // ---- main: groups 7..126 in 15 blocks of 8 (slot == k, parity static) ----
    for (int o = 0; o < 15; ++o) {
        const int gbase = 7 + 8 * o;
        GROUP(gbase + 0, 0, N00, N01, N02, N03, N10, N11, N12, N13, C00, C01, C02, C03, C10, C11, C12, C13)
        GROUP(gbase + 1, 1, C00, C01, C02, C03, C10, C11, C12, C13, N00, N01, N02, N03, N10, N11, N12, N13)
        GROUP(gbase + 2, 2, N00, N01, N02, N03, N10, N11, N12, N13, C00, C01, C02, C03, C10, C11, C12, C13)
        GROUP(gbase + 3, 3, C00, C01, C02, C03, C10, C11, C12, C13, N00, N01, N02, N03, N10, N11, N12, N13)
        GROUP(gbase + 4, 4, N00, N01, N02, N03, N10, N11, N12, N13, C00, C01, C02, C03, C10, C11, C12, C13)
        GROUP(gbase + 5, 5, C00, C01, C02, C03, C10, C11, C12, C13, N00, N01, N02, N03, N10, N11, N12, N13)
        GROUP(gbase + 6, 6, N00, N01, N02, N03, N10, N11, N12, N13, C00, C01, C02, C03, C10, C11, C12, C13)
        GROUP(gbase + 7, 7, C00, C01, C02, C03, C10, C11, C12, C13, N00, N01, N02, N03, N10, N11, N12, N13)
        // renorm every 32 steps (same cadence/count as verified kernel: 15x)
        float vm = fmaxf(A0, v1 ? A1 : 0.f);
        float m = wave_max(vm);
        int ebits = (f2i(m) >> 23) & 0xFF;
        float sc = i2f((254 - ebits) << 23);   // 2^(127 - ebits)
        A0 *= sc;
        A1 = v1 ? A1 * sc : 0.f;
        S2 += ebits - 127;
    }

    // ---- final group 127 (odd -> uses N), t = 508..511 ----
    stageB(N00, N10);
    stageB(N01, N11);
    stageB(N02, N12);
    stageB(N03, N13);

    float aLast = i2f(__builtin_amdgcn_readlane(f2i(A1), 32));  // s = 96
    float aPrev = i2f(__builtin_amdgcn_readlane(f2i(A1), 31));  // s = 95
    if (l == 0) {
        // stored = true * 96^512 * 2^(-S2)
        loss[b] = 2336.946274031532f
                - (float)S2 * 0.6931471805599453f
                - __logf(aLast + aPrev);
    }
#undef GROUP
#undef COMPUTE_E
}

// ---------------------------------------------------------------------------
// Fallback: the previous verified single-pass kernel (used if ws too small).
// ---------------------------------------------------------------------------
__global__ __launch_bounds__(64) void ctc_fused_lin(
        const int* __restrict__ labels,
        const float* __restrict__ yp,
        float* __restrict__ loss) {
    const int b = blockIdx.x;
    const int l = threadIdx.x;
    const int* lb = labels + b * LL;

    const bool odd = (l & 1);
    const int i0 = l >> 1;
    int i1 = (63 + l) >> 1; if (i1 > LL - 1) i1 = LL - 1;
    const int la0 = lb[i0];
    const int lp0 = lb[(i0 > 0) ? i0 - 1 : 0];
    const int la1 = lb[i1];
    const int lp1 = lb[(i1 > 0) ? i1 - 1 : 0];
    const bool v1 = (l <= 32);
    const bool skip0 = odd && (l >= 3) && (la0 != lp0);
    const bool skip1 = odd && v1 && (la1 != lp1);
    const int id0 = odd ? la0 : 0;
    const int id1 = (odd && v1) ? la1 : 0;
    const int pa0 = (id0 >> 1) << 2, ps0 = id0 & 1;
    const int pa1 = (id1 >> 1) << 2, ps1 = id1 & 1;

    const int cl = (l < 48) ? l : 47;
    const float2* rowp = (const float2*)yp + (size_t)b * (VV / 2) + cl;
    const size_t step2 = (size_t)BB * (VV / 2);

    float2 ring[8];
    #pragma unroll
    for (int j = 0; j < 8; ++j) ring[j] = rowp[(size_t)j * step2];

    float Ec0, Ec1;
    float A0, A1;
    int S2 = 0;

    auto stageA = [&](float2 r) {
        float ex0 = __expf(r.x), ex1 = __expf(r.y);
        float se = (l < 48) ? (ex0 + ex1) : 0.f;
        float tot = wave_sum(se);
        float r96 = 96.0f * __builtin_amdgcn_rcpf(tot);
        float g0x = i2f(__builtin_amdgcn_ds_bpermute(pa0, f2i(ex0)));
        float g0y = i2f(__builtin_amdgcn_ds_bpermute(pa0, f2i(ex1)));
        float g1x = i2f(__builtin_amdgcn_ds_bpermute(pa1, f2i(ex0)));
        float g1y = i2f(__builtin_amdgcn_ds_bpermute(pa1, f2i(ex1)));
        Ec0 = (ps0 ? g0y : g0x) * r96;
        Ec1 = (ps1 ? g1y : g1x) * r96;
    };

    auto stageB = [&]() {
        float a1_0 = dppf<0x138, 0xF, 0xF, false>(0.f, A0);
        float a2_0 = dppf<0x138, 0xF, 0xF, false>(0.f, a1_0);
        float b63 = i2f(__builtin_amdgcn_readlane(f2i(A0), 63));
        float b62 = i2f(__builtin_amdgcn_readlane(f2i(A0), 62));
        float a1_1 = dppf<0x138, 0xF, 0xF, false>(b63, A1);
        float a2_1 = dppf<0x138, 0xF, 0xF, false>(b62, a1_1);
        A0 = (A0 + a1_0 + (skip0 ? a2_0 : 0.f)) * Ec0;
        A1 = (A1 + a1_1 + (skip1 ? a2_1 : 0.f)) * Ec1;
    };

    stageA(ring[0]);
    A0 = (l < 2) ? Ec0 : 0.f;
    A1 = 0.f;
    ring[0] = rowp[(size_t)8 * step2];
    stageA(ring[1]);
    ring[1] = rowp[(size_t)9 * step2];

    #pragma unroll
    for (int t = 1; t <= 6; ++t) {
        stageB();
        stageA(ring[(t + 1) & 7]);
        ring[(t + 1) & 7] = rowp[(size_t)(t + 9) * step2];
    }

    for (int o = 0; o < 63; ++o) {
        #pragma unroll
        for (int tt = 0; tt < 8; ++tt) {
            const int t = 7 + 8 * o + tt;
            stageB();
            stageA(ring[tt]);
            int tl = t + 9; if (tl > TT - 1) tl = TT - 1;
            ring[tt] = rowp[(size_t)tl * step2];
        }
        if ((o & 3) == 3) {
            float vm = fmaxf(A0, v1 ? A1 : 0.f);
            float m = wave_max(vm);
            int ebits = (f2i(m) >> 23) & 0xFF;
            float sc = i2f((254 - ebits) << 23);
            A0 *= sc;
            A1 = v1 ? A1 * sc : 0.f;
            S2 += ebits - 127;
        }
    }

    stageB();

    float aLast = i2f(__builtin_amdgcn_readlane(f2i(A1), 32));
    float aPrev = i2f(__builtin_amdgcn_readlane(f2i(A1), 31));
    if (l == 0) {
        loss[b] = 2336.946274031532f
                - (float)S2 * 0.6931471805599453f
                - __logf(aLast + aPrev);
    }
}

__global__ __launch_bounds__(256) void ctc_mean_kernel(
        const float* __restrict__ loss, float* __restrict__ out) {
    const int tid = threadIdx.x;
    float v = loss[tid] + loss[tid + 256] + loss[tid + 512] + loss[tid + 768];
    #pragma unroll
    for (int m = 1; m < 64; m <<= 1) v += __shfl_xor(v, m);
    __shared__ float part[4];
    if ((tid & 63) == 0) part[tid >> 6] = v;
    __syncthreads();
    if (tid == 0) out[0] = (part[0] + part[1] + part[2] + part[3]) * (1.0f / (float)BB);
}

extern "C" void kernel_launch(void* const* d_in, const int* in_sizes, int n_in,
                              void* d_out, int out_size, void* d_ws, size_t ws_size,
                              hipStream_t stream) {
    const int* y_true = (const int*)d_in[0];     // [B, L] int32
    const float* y_pred = (const float*)d_in[1]; // [T, B, V] float32
    float* out = (float*)d_out;

    const size_t PBYTES = (size_t)BB * TG * SLOT * sizeof(float4);  // ~104 MiB

    if (ws_size >= PBYTES + 4096) {
        float4* P = (float4*)d_ws;
        float* lossbuf = (float*)((char*)d_ws + PBYTES);
        ctc_emit<<<(BB * TG) / 4, 256, 0, stream>>>(y_true, y_pred, P);
        ctc_scan<<<BB, 64, 0, stream>>>(y_true, P, lossbuf);
        ctc_mean_kernel<<<1, 256, 0, stream>>>(lossbuf, out);
    } else {
        // workspace too small for the emission table: proven single-pass path
        float* lossbuf = (float*)d_ws;
        ctc_fused_lin<<<BB, 64, 0, stream>>>(y_true, y_pred, lossbuf);
        ctc_mean_kernel<<<1, 256, 0, stream>>>(lossbuf, out);
    }
}

// Round 2
// 288.685 us; speedup vs baseline: 1.1618x; 1.1618x over previous
//
#include <hip/hip_runtime.h>

#define TT 512
#define BB 1024
#define VV 96
#define LL 48

__device__ __forceinline__ int f2i(float x) { return __float_as_int(x); }
__device__ __forceinline__ float i2f(int x) { return __int_as_float(x); }

template <int CTRL, int RM, int BM, bool BC>
__device__ __forceinline__ float dppf(float old, float src) {
    return i2f(__builtin_amdgcn_update_dpp(f2i(old), f2i(src), CTRL, RM, BM, BC));
}

// Full-wave sum via DPP butterfly (verified rounds 2-3); broadcast via lane 63.
__device__ __forceinline__ float wave_sum(float v) {
    v += dppf<0xB1, 0xF, 0xF, true>(0.f, v);   // quad_perm [1,0,3,2]
    v += dppf<0x4E, 0xF, 0xF, true>(0.f, v);   // quad_perm [2,3,0,1]
    v += dppf<0x141, 0xF, 0xF, true>(0.f, v);  // row_half_mirror
    v += dppf<0x140, 0xF, 0xF, true>(0.f, v);  // row_mirror
    v += dppf<0x142, 0xA, 0xF, false>(0.f, v); // row_bcast15
    v += dppf<0x143, 0xC, 0xF, false>(0.f, v); // row_bcast31
    return i2f(__builtin_amdgcn_readlane(f2i(v), 63));
}

// Full-wave max (nonnegative inputs; old=0 is neutral).
__device__ __forceinline__ float wave_max(float v) {
    v = fmaxf(v, dppf<0xB1, 0xF, 0xF, true>(0.f, v));
    v = fmaxf(v, dppf<0x4E, 0xF, 0xF, true>(0.f, v));
    v = fmaxf(v, dppf<0x141, 0xF, 0xF, true>(0.f, v));
    v = fmaxf(v, dppf<0x140, 0xF, 0xF, true>(0.f, v));
    v = fmaxf(v, dppf<0x142, 0xA, 0xF, false>(0.f, v));
    v = fmaxf(v, dppf<0x143, 0xC, 0xF, false>(0.f, v));
    return i2f(__builtin_amdgcn_readlane(f2i(v), 63));
}

// One wave per batch element. Linear-space scaled CTC forward, single pass
// over y_pred, 8-row register prefetch ring, E pipelined FOUR steps ahead
// (4 E-slot pairs indexed by t&3; stageA at step t produces E(t+4), so the
// exp->wave_sum->rcp->bpermute chain has ~4 steps of independent work
// between production and consumption even with zero compiler reordering).
__global__ __launch_bounds__(64) void ctc_fused_lin(
        const int* __restrict__ labels,
        const float* __restrict__ yp,
        float* __restrict__ loss) {
    const int b = blockIdx.x;
    const int l = threadIdx.x;
    const int* lb = labels + b * LL;

    // ---- per-lane constants (state mapping verified in rounds 1-3) ----
    const bool odd = (l & 1);
    const int i0 = l >> 1;
    int i1 = (63 + l) >> 1; if (i1 > LL - 1) i1 = LL - 1;
    const int la0 = lb[i0];
    const int lp0 = lb[(i0 > 0) ? i0 - 1 : 0];
    const int la1 = lb[i1];
    const int lp1 = lb[(i1 > 0) ? i1 - 1 : 0];
    const bool v1 = (l <= 32);
    const bool skip0 = odd && (l >= 3) && (la0 != lp0);
    const bool skip1 = odd && v1 && (la1 != lp1);
    const int id0 = odd ? la0 : 0;           // vocab id for state s0 = l
    const int id1 = (odd && v1) ? la1 : 0;   // vocab id for state s1 = 64+l
    const int pa0 = (id0 >> 1) << 2, ps0 = id0 & 1;
    const int pa1 = (id1 >> 1) << 2, ps1 = id1 & 1;

    const int cl = (l < 48) ? l : 47;        // float2 slot loaded by this lane
    const float2* rowp = (const float2*)yp + (size_t)b * (VV / 2) + cl;
    const size_t step2 = (size_t)BB * (VV / 2);

    // ---- 8-row register prefetch ring ----
    float2 ring[8];
    #pragma unroll
    for (int j = 0; j < 8; ++j) ring[j] = rowp[(size_t)j * step2];

    float A0, A1;         // alpha (linear, rescaled); A0: s=l, A1: s=64+l
    int S2 = 0;           // accumulated log2 scale removed by renorms

    // 4 E-slot pairs (slot = t & 3), all named scalars (static indexing)
    float E00, E01, E10, E11, E20, E21, E30, E31;

    // stage A: row -> E = 96 * softmax(row)[ext[s]] for both owned states
#define STAGEA(r, EO0, EO1) { \
        float ex0 = __expf((r).x), ex1 = __expf((r).y); \
        float se = (l < 48) ? (ex0 + ex1) : 0.f; \
        float tot = wave_sum(se); \
        float r96 = 96.0f * __builtin_amdgcn_rcpf(tot); \
        float g0x = i2f(__builtin_amdgcn_ds_bpermute(pa0, f2i(ex0))); \
        float g0y = i2f(__builtin_amdgcn_ds_bpermute(pa0, f2i(ex1))); \
        float g1x = i2f(__builtin_amdgcn_ds_bpermute(pa1, f2i(ex0))); \
        float g1y = i2f(__builtin_amdgcn_ds_bpermute(pa1, f2i(ex1))); \
        EO0 = (ps0 ? g0y : g0x) * r96; \
        EO1 = (ps1 ? g1y : g1x) * r96; }

    // stage B: linear alpha update (no transcendentals)
    auto stageB = [&](float e0, float e1) {
        float a1_0 = dppf<0x138, 0xF, 0xF, false>(0.f, A0);      // wave_shr1
        float a2_0 = dppf<0x138, 0xF, 0xF, false>(0.f, a1_0);
        float b63 = i2f(__builtin_amdgcn_readlane(f2i(A0), 63));
        float b62 = i2f(__builtin_amdgcn_readlane(f2i(A0), 62));
        float a1_1 = dppf<0x138, 0xF, 0xF, false>(b63, A1);
        float a2_1 = dppf<0x138, 0xF, 0xF, false>(b62, a1_1);
        A0 = (A0 + a1_0 + (skip0 ? a2_0 : 0.f)) * e0;
        A1 = (A1 + a1_1 + (skip1 ? a2_1 : 0.f)) * e1;
    };

    // step t: consume E(t) from slot t&3; produce E(t+4) into the same slot,
    // reading ring[(t+4)&7] (row t+4); refill that ring slot with row t+12.
#define STEP(T, RS, EA, EB) \
        stageB(EA, EB); \
        STAGEA(ring[RS], EA, EB); \
        { int tl = (T) + 12; if (tl > TT - 1) tl = TT - 1; \
          ring[RS] = rowp[(size_t)tl * step2]; }

#define STEPN(RS, EA, EB) \
        stageB(EA, EB); \
        STAGEA(ring[RS], EA, EB);

    // ---- init: compute E(0..4), consume E(0) for t=0 ----
    STAGEA(ring[0], E00, E01);             // E(0)
    A0 = (l < 2) ? E00 : 0.f;
    A1 = 0.f;
    ring[0] = rowp[(size_t)8 * step2];
    STAGEA(ring[1], E10, E11);             // E(1)
    ring[1] = rowp[(size_t)9 * step2];
    STAGEA(ring[2], E20, E21);             // E(2)
    ring[2] = rowp[(size_t)10 * step2];
    STAGEA(ring[3], E30, E31);             // E(3)
    ring[3] = rowp[(size_t)11 * step2];
    STAGEA(ring[4], E00, E01);             // E(4) -> slot 0 (E(0) consumed)
    ring[4] = rowp[(size_t)12 * step2];

    // ---- prologue t = 1..6 ----
    STEP(1, 5, E10, E11)
    STEP(2, 6, E20, E21)
    STEP(3, 7, E30, E31)
    STEP(4, 0, E00, E01)
    STEP(5, 1, E10, E11)
    STEP(6, 2, E20, E21)

    // ---- main t = 7..502 (62 blocks of 8; renorm every 32 steps, 15x) ----
    for (int o = 0; o < 62; ++o) {
        const int t0 = 7 + 8 * o;
        STEP(t0 + 0, 3, E30, E31)
        STEP(t0 + 1, 4, E00, E01)
        STEP(t0 + 2, 5, E10, E11)
        STEP(t0 + 3, 6, E20, E21)
        STEP(t0 + 4, 7, E30, E31)
        STEP(t0 + 5, 0, E00, E01)
        STEP(t0 + 6, 1, E10, E11)
        STEP(t0 + 7, 2, E20, E21)
        if ((o & 3) == 3) {                // renorm every 32 steps
            float vm = fmaxf(A0, v1 ? A1 : 0.f);
            float m = wave_max(vm);
            int ebits = (f2i(m) >> 23) & 0xFF;
            float sc = i2f((254 - ebits) << 23);   // 2^(127 - ebits)
            A0 *= sc;
            A1 = v1 ? A1 * sc : 0.f;
            S2 += ebits - 127;
        }
    }

    // ---- peeled tail t = 503..507 (still producing E(507..511)) ----
    STEPN(3, E30, E31)   // t=503 -> E(507)
    STEPN(4, E00, E01)   // t=504 -> E(508)
    STEPN(5, E10, E11)   // t=505 -> E(509)
    STEPN(6, E20, E21)   // t=506 -> E(510)
    STEPN(7, E30, E31)   // t=507 -> E(511)

    // ---- t = 508..511: consume remaining E slots ----
    stageB(E00, E01);    // t=508
    stageB(E10, E11);    // t=509
    stageB(E20, E21);    // t=510
    stageB(E30, E31);    // t=511

    float aLast = i2f(__builtin_amdgcn_readlane(f2i(A1), 32));  // s = 96
    float aPrev = i2f(__builtin_amdgcn_readlane(f2i(A1), 31));  // s = 95
    if (l == 0) {
        // stored = true * 96^512 * 2^(-S2)  =>  -ln(true) = 512*ln96 - S2*ln2 - ln(stored)
        loss[b] = 2336.946274031532f
                - (float)S2 * 0.6931471805599453f
                - __logf(aLast + aPrev);
    }
#undef STEP
#undef STEPN
#undef STAGEA
}

__global__ __launch_bounds__(256) void ctc_mean_kernel(
        const float* __restrict__ loss, float* __restrict__ out) {
    const int tid = threadIdx.x;
    float v = loss[tid] + loss[tid + 256] + loss[tid + 512] + loss[tid + 768];
    #pragma unroll
    for (int m = 1; m < 64; m <<= 1) v += __shfl_xor(v, m);
    __shared__ float part[4];
    if ((tid & 63) == 0) part[tid >> 6] = v;
    __syncthreads();
    if (tid == 0) out[0] = (part[0] + part[1] + part[2] + part[3]) * (1.0f / (float)BB);
}

extern "C" void kernel_launch(void* const* d_in, const int* in_sizes, int n_in,
                              void* d_out, int out_size, void* d_ws, size_t ws_size,
                              hipStream_t stream) {
    const int* y_true = (const int*)d_in[0];     // [B, L] int32
    const float* y_pred = (const float*)d_in[1]; // [T, B, V] float32
    float* out = (float*)d_out;
    float* lossbuf = (float*)d_ws;               // [B] floats

    ctc_fused_lin<<<BB, 64, 0, stream>>>(y_true, y_pred, lossbuf);
    ctc_mean_kernel<<<1, 256, 0, stream>>>(lossbuf, out);
}

// Round 5
// 283.170 us; speedup vs baseline: 1.1844x; 1.0195x over previous
//
#include <hip/hip_runtime.h>

#define TT 512
#define BB 1024
#define VV 96
#define LL 48

__device__ __forceinline__ int f2i(float x) { return __float_as_int(x); }
__device__ __forceinline__ float i2f(int x) { return __int_as_float(x); }

template <int CTRL, int RM, int BM, bool BC>
__device__ __forceinline__ float dppf(float old, float src) {
    return i2f(__builtin_amdgcn_update_dpp(f2i(old), f2i(src), CTRL, RM, BM, BC));
}

// Full-wave sum via DPP butterfly (verified); broadcast via lane 63.
__device__ __forceinline__ float wave_sum(float v) {
    v += dppf<0xB1, 0xF, 0xF, true>(0.f, v);   // quad_perm [1,0,3,2]
    v += dppf<0x4E, 0xF, 0xF, true>(0.f, v);   // quad_perm [2,3,0,1]
    v += dppf<0x141, 0xF, 0xF, true>(0.f, v);  // row_half_mirror
    v += dppf<0x140, 0xF, 0xF, true>(0.f, v);  // row_mirror
    v += dppf<0x142, 0xA, 0xF, false>(0.f, v); // row_bcast15
    v += dppf<0x143, 0xC, 0xF, false>(0.f, v); // row_bcast31
    return i2f(__builtin_amdgcn_readlane(f2i(v), 63));
}

// Full-wave max (nonnegative inputs; old=0 is neutral).
__device__ __forceinline__ float wave_max(float v) {
    v = fmaxf(v, dppf<0xB1, 0xF, 0xF, true>(0.f, v));
    v = fmaxf(v, dppf<0x4E, 0xF, 0xF, true>(0.f, v));
    v = fmaxf(v, dppf<0x141, 0xF, 0xF, true>(0.f, v));
    v = fmaxf(v, dppf<0x140, 0xF, 0xF, true>(0.f, v));
    v = fmaxf(v, dppf<0x142, 0xA, 0xF, false>(0.f, v));
    v = fmaxf(v, dppf<0x143, 0xC, 0xF, false>(0.f, v));
    return i2f(__builtin_amdgcn_readlane(f2i(v), 63));
}

// Two waves per batch element:
//   wave 0: forward  alpha_255 = M_255..M_0 * delta0       (256 steps, shift-right)
//   wave 1: backward v = M_256^T..M_511^T * (e95+e96)      (256 steps, shift-left)
// loss = 512*ln96 - (S2a+S2b)*ln2 - ln(dot(alpha_255, v)).
// The dot can be ~2^-134 (forward/backward peaks misalign) -> computed in f64
// with exponent extracted via bit ops (round-4 fix for f32 underflow -> inf).
__global__ __launch_bounds__(128) void ctc_fused_split(
        const int* __restrict__ labels,
        const float* __restrict__ yp,
        float* __restrict__ loss) {
    const int b = blockIdx.x;
    const int tid = threadIdx.x;
    const int wid = tid >> 6;
    const int l = tid & 63;
    const int* lb = labels + b * LL;

    // ---- per-lane constants (state mapping verified in prior rounds) ----
    const bool odd = (l & 1);
    const int i0 = l >> 1;
    int i1 = (63 + l) >> 1; if (i1 > LL - 1) i1 = LL - 1;
    const int la0 = lb[i0];
    const int lp0 = lb[(i0 > 0) ? i0 - 1 : 0];
    const int la1 = lb[i1];
    const int lp1 = lb[(i1 > 0) ? i1 - 1 : 0];
    const bool v1 = (l <= 32);
    // forward: skip[s] at own state s (s0=l, s1=64+l)
    const bool skip0 = odd && (l >= 3) && (la0 != lp0);
    const bool skip1 = odd && v1 && (la1 != lp1);
    // backward: skip[s+2] (state l+2 resp. 66+l); label idx i0+1 / i1+1
    int i0n = i0 + 1; if (i0n > LL - 1) i0n = LL - 1;
    int i1n = i1 + 1; if (i1n > LL - 1) i1n = LL - 1;
    const bool skT0 = odd && (lb[i0n] != la0);             // skip[l+2], l+2 <= 65
    const bool skT1 = odd && (l < 31) && (lb[i1n] != la1); // skip[66+l], 66+l <= 96

    const int id0 = odd ? la0 : 0;           // vocab id for state s0 = l
    const int id1 = (odd && v1) ? la1 : 0;   // vocab id for state s1 = 64+l
    const int pa0 = (id0 >> 1) << 2, ps0 = id0 & 1;
    const int pa1 = (id1 >> 1) << 2, ps1 = id1 & 1;

    const int cl = (l < 48) ? l : 47;        // float2 slot loaded by this lane
    const float2* rowp = (const float2*)yp + (size_t)b * (VV / 2) + cl;
    const size_t step2 = (size_t)BB * (VV / 2);

    float2 ring[8];
    float A0, A1;         // wave0: alpha; wave1: beta/v  (A0: s=l, A1: s=64+l)
    int S2 = 0;
    float EP0, EP1;       // E(current step), one step of lookahead

    // stage A: row -> E = 96 * softmax(row)[ext[s]] for both owned states
#define STAGEA(r, EO0, EO1) { \
        float ex0 = __expf((r).x), ex1 = __expf((r).y); \
        float se = (l < 48) ? (ex0 + ex1) : 0.f; \
        float tot = wave_sum(se); \
        float r96 = 96.0f * __builtin_amdgcn_rcpf(tot); \
        float g0x = i2f(__builtin_amdgcn_ds_bpermute(pa0, f2i(ex0))); \
        float g0y = i2f(__builtin_amdgcn_ds_bpermute(pa0, f2i(ex1))); \
        float g1x = i2f(__builtin_amdgcn_ds_bpermute(pa1, f2i(ex0))); \
        float g1y = i2f(__builtin_amdgcn_ds_bpermute(pa1, f2i(ex1))); \
        EO0 = (ps0 ? g0y : g0x) * r96; \
        EO1 = (ps1 ? g1y : g1x) * r96; }

#define RENORM { \
        float vm = fmaxf(A0, v1 ? A1 : 0.f); \
        float m = wave_max(vm); \
        int ebits = (f2i(m) >> 23) & 0xFF; \
        float sc = i2f((254 - ebits) << 23); \
        A0 *= sc; \
        A1 = v1 ? A1 * sc : 0.f; \
        S2 += ebits - 127; }

    __shared__ float sB0[64];
    __shared__ float sB1[33];
    __shared__ int sS2b;

    if (wid == 0) {
        // ---------------- forward chunk: rows 0..255 ----------------
        #pragma unroll
        for (int j = 0; j < 8; ++j) ring[j] = rowp[(size_t)j * step2];
        // alpha "t=-1" init: delta at s=0; first update (E(0)) yields
        // alpha0[0]=E0[0], alpha0[1]=E0[1], rest 0 (skip[1]=skip[2]=false).
        A0 = (l == 0) ? 1.f : 0.f;
        A1 = 0.f;
        STAGEA(ring[0], EP0, EP1);             // E(0)
        ring[0] = rowp[(size_t)8 * step2];
        for (int o = 0; o < 8; ++o) {
            for (int u = 0; u < 4; ++u) {
                #pragma unroll
                for (int tt = 0; tt < 8; ++tt) {
                    const int k = 32 * o + 8 * u + tt;   // k & 7 == tt
                    // forward update with E(k)
                    float a1_0 = dppf<0x138, 0xF, 0xF, false>(0.f, A0);
                    float a2_0 = dppf<0x138, 0xF, 0xF, false>(0.f, a1_0);
                    float b63 = i2f(__builtin_amdgcn_readlane(f2i(A0), 63));
                    float b62 = i2f(__builtin_amdgcn_readlane(f2i(A0), 62));
                    float a1_1 = dppf<0x138, 0xF, 0xF, false>(b63, A1);
                    float a2_1 = dppf<0x138, 0xF, 0xF, false>(b62, a1_1);
                    A0 = (A0 + a1_0 + (skip0 ? a2_0 : 0.f)) * EP0;
                    A1 = (A1 + a1_1 + (skip1 ? a2_1 : 0.f)) * EP1;
                    // E(k+1) from ring slot (tt+1)&7 (holds row k+1); refill k+9
                    STAGEA(ring[(tt + 1) & 7], EP0, EP1);
                    int kr = k + 9; if (kr > 255) kr = 255;  // clamp (tail rows unused)
                    ring[(tt + 1) & 7] = rowp[(size_t)kr * step2];
                }
            }
            RENORM
        }
    } else {
        // ---------------- backward chunk: rows 511..256 ----------------
        #pragma unroll
        for (int j = 0; j < 8; ++j) ring[j] = rowp[(size_t)(511 - j) * step2];
        A0 = 0.f;
        A1 = (l == 31 || l == 32) ? 1.f : 0.f;   // u = e95 + e96
        STAGEA(ring[0], EP0, EP1);               // E(511)
        ring[0] = rowp[(size_t)(511 - 8) * step2];
        for (int o = 0; o < 8; ++o) {
            for (int u = 0; u < 4; ++u) {
                #pragma unroll
                for (int tt = 0; tt < 8; ++tt) {
                    const int k = 32 * o + 8 * u + tt;   // applies row 511-k
                    // v' = L^T (E .* v): w = E.*v, then left shifts
                    float w0 = A0 * EP0;
                    float w1 = A1 * EP1;
                    float t0 = i2f(__builtin_amdgcn_readlane(f2i(w1), 0)); // w[64]
                    float t1 = i2f(__builtin_amdgcn_readlane(f2i(w1), 1)); // w[65]
                    float s1_0 = dppf<0x130, 0xF, 0xF, false>(t0, w0);  // w[l+1]
                    float s2_0 = dppf<0x130, 0xF, 0xF, false>(t1, s1_0);// w[l+2]
                    float s1_1 = dppf<0x130, 0xF, 0xF, false>(0.f, w1); // w[65+l]
                    float s2_1 = dppf<0x130, 0xF, 0xF, false>(0.f, s1_1);// w[66+l]
                    A0 = w0 + s1_0 + (skT0 ? s2_0 : 0.f);
                    A1 = w1 + s1_1 + (skT1 ? s2_1 : 0.f);
                    STAGEA(ring[(tt + 1) & 7], EP0, EP1);   // E(511-(k+1))
                    int kr = k + 9; if (kr > 255) kr = 255;
                    ring[(tt + 1) & 7] = rowp[(size_t)(511 - kr) * step2];
                }
            }
            RENORM
        }
        sB0[l] = A0;
        if (l < 33) sB1[l] = A1;
        if (l == 0) sS2b = S2;
    }
    __syncthreads();
    if (wid == 0) {
        // f64 dot: components can be ~2^-130 (f32-underflow) but >> 2^-1022.
        const int lc = (l < 33) ? l : 32;
        double pd = (double)A0 * (double)sB0[l];
        pd += v1 ? (double)A1 * (double)sB1[lc] : 0.0;
        #pragma unroll
        for (int m = 1; m < 64; m <<= 1) pd += __shfl_xor(pd, m);
        if (l == 0) {
            // pd = true * 96^512 * 2^(-S2a-S2b); peel exponent via bits.
            long long ud = __double_as_longlong(pd);
            int eb = (int)((ud >> 52) & 0x7FF);             // biased exponent
            double md = __longlong_as_double(
                (ud & 0x000FFFFFFFFFFFFFLL) | 0x3FF0000000000000LL); // [1,2)
            int s2tot = S2 + sS2b + (eb - 1023);
            loss[b] = 2336.946274031532f
                    - (float)s2tot * 0.6931471805599453f
                    - __logf((float)md);
        }
    }
#undef STAGEA
#undef RENORM
}

__global__ __launch_bounds__(256) void ctc_mean_kernel(
        const float* __restrict__ loss, float* __restrict__ out) {
    const int tid = threadIdx.x;
    float v = loss[tid] + loss[tid + 256] + loss[tid + 512] + loss[tid + 768];
    #pragma unroll
    for (int m = 1; m < 64; m <<= 1) v += __shfl_xor(v, m);
    __shared__ float part[4];
    if ((tid & 63) == 0) part[tid >> 6] = v;
    __syncthreads();
    if (tid == 0) out[0] = (part[0] + part[1] + part[2] + part[3]) * (1.0f / (float)BB);
}

extern "C" void kernel_launch(void* const* d_in, const int* in_sizes, int n_in,
                              void* d_out, int out_size, void* d_ws, size_t ws_size,
                              hipStream_t stream) {
    const int* y_true = (const int*)d_in[0];     // [B, L] int32
    const float* y_pred = (const float*)d_in[1]; // [T, B, V] float32
    float* out = (float*)d_out;
    float* lossbuf = (float*)d_ws;               // [B] floats

    ctc_fused_split<<<BB, 128, 0, stream>>>(y_true, y_pred, lossbuf);
    ctc_mean_kernel<<<1, 256, 0, stream>>>(lossbuf, out);
}